// Round 8
// baseline (344.645 us; speedup 1.0000x reference)
//
#include <hip/hip_runtime.h>
#include <hip/hip_bf16.h>

typedef __attribute__((ext_vector_type(8))) short short8;
typedef __attribute__((ext_vector_type(4))) short short4v;
typedef __attribute__((ext_vector_type(4))) float f32x4;

#define Dk 1024
#define TT 2048
#define BB 8
#define MROWS (BB * TT)   // 16384
#define LOG2E 1.44269504088896f

#if defined(__has_builtin)
#if __has_builtin(__builtin_amdgcn_rcpf)
#define FAST_RCP(x) __builtin_amdgcn_rcpf(x)
#endif
#if __has_builtin(__builtin_amdgcn_exp2f)
#define FAST_EXP2(x) __builtin_amdgcn_exp2f(x)
#endif
#endif
#ifndef FAST_RCP
#define FAST_RCP(x) (1.f / (x))
#endif
#ifndef FAST_EXP2
#define FAST_EXP2(x) exp2f(x)
#endif

__device__ __forceinline__ void gload_lds16(const void* g, void* l) {
    __builtin_amdgcn_global_load_lds(
        (const __attribute__((address_space(1))) void*)g,
        (__attribute__((address_space(3))) void*)l, 16, 0, 0);
}

__device__ __forceinline__ float sigmoidf_fast(float x) {
    return FAST_RCP(1.f + FAST_EXP2(-x * LOG2E));
}

__device__ __forceinline__ unsigned short bf16_bits(float x) {
    union { __hip_bfloat16 h; unsigned short u; } c;
    c.h = __float2bfloat16(x);
    return c.u;
}

// fp32 -> bf16, 4 elems/thread
__global__ __launch_bounds__(256)
void cvt_f32_bf16(const float* __restrict__ in, __hip_bfloat16* __restrict__ out, int n) {
    const int i = (blockIdx.x * 256 + threadIdx.x) * 4;
    if (i >= n) return;
    const float4 v = *(const float4*)(in + i);
    __hip_bfloat16 tmp[4];
    tmp[0] = __float2bfloat16(v.x);
    tmp[1] = __float2bfloat16(v.y);
    tmp[2] = __float2bfloat16(v.z);
    tmp[3] = __float2bfloat16(v.w);
    *(short4v*)(out + i) = *(const short4v*)tmp;
}

// all four 1024x1024 weights in one launch
__global__ __launch_bounds__(256)
void cvt_w4(const float* __restrict__ w0, const float* __restrict__ w1,
            const float* __restrict__ w2, const float* __restrict__ w3,
            __hip_bfloat16* __restrict__ o0, __hip_bfloat16* __restrict__ o1,
            __hip_bfloat16* __restrict__ o2, __hip_bfloat16* __restrict__ o3)
{
    const int which = blockIdx.x >> 10;
    const int i = ((blockIdx.x & 1023) * 256 + threadIdx.x) * 4;
    const float* in = which == 0 ? w0 : which == 1 ? w1 : which == 2 ? w2 : w3;
    __hip_bfloat16* out = which == 0 ? o0 : which == 1 ? o1 : which == 2 ? o2 : o3;
    const float4 v = *(const float4*)(in + i);
    __hip_bfloat16 tmp[4];
    tmp[0] = __float2bfloat16(v.x);
    tmp[1] = __float2bfloat16(v.y);
    tmp[2] = __float2bfloat16(v.z);
    tmp[3] = __float2bfloat16(v.w);
    *(short4v*)(out + i) = *(const short4v*)tmp;
}

// C = epi(A * B^T). A: [M x 1024] bf16 rm, Bw: [1024 x 1024] bf16 rm.
// 3-buffer LDS pipeline with counted vmcnt: stage k+2 while computing k;
// s_waitcnt vmcnt(4) retires only tile k+1's loads (never drain to 0 in loop).
// EPI: 0 silu->bf16 | 1 plain->f32
//      6 E=exp(-(x+bias)) -> u16 @2*idx | 7 V=tanh(x+bias) -> u16 @2*idx+1
template<int EPI>
__global__ __launch_bounds__(256)
void gemm_bt(const __hip_bfloat16* __restrict__ A,
             const __hip_bfloat16* __restrict__ Bw,
             const float* __restrict__ bias,
             void* __restrict__ CoutV)
{
    __shared__ __hip_bfloat16 sA[3][128 * 32];
    __shared__ __hip_bfloat16 sB[3][128 * 32];

    const int tid  = threadIdx.x;
    const int bid  = blockIdx.x;
    const int nbid = (bid & 7) * 128 + (bid >> 3);   // XCD swizzle
    const int tn   = nbid & 7;
    const int tm   = nbid >> 3;
    const int lane = tid & 63;
    const int w    = tid >> 6;
    const int wr   = (w >> 1) * 64;
    const int wc   = (w & 1) * 64;
    const int l15  = lane & 15;
    const int lq   = lane >> 4;

    f32x4 acc[4][4];
#pragma unroll
    for (int m = 0; m < 4; ++m)
#pragma unroll
        for (int n = 0; n < 4; ++n)
            acc[m][n] = (f32x4){0.f, 0.f, 0.f, 0.f};

    const size_t baseA = (size_t)(tm * 128) * Dk;
    const size_t baseB = (size_t)(tn * 128) * Dk;

    // 4 VMEM ops per thread per stage
    auto stage = [&](int k0, int buf) {
#pragma unroll
        for (int i = 0; i < 2; ++i) {
            const int li  = i * 256 + tid;
            const int row = li >> 2;
            const int cb  = li & 3;
            const size_t go = (size_t)row * Dk + k0 + cb * 8;
            gload_lds16(A  + baseA + go, (char*)sA[buf] + li * 16);
            gload_lds16(Bw + baseB + go, (char*)sB[buf] + li * 16);
        }
    };

    auto compute = [&](int buf) {
        short8 af[4], bfr[4];
#pragma unroll
        for (int m = 0; m < 4; ++m)
            af[m] = *(const short8*)(sA[buf] + (wr + m * 16 + l15) * 32 + lq * 8);
#pragma unroll
        for (int n = 0; n < 4; ++n)
            bfr[n] = *(const short8*)(sB[buf] + (wc + n * 16 + l15) * 32 + lq * 8);
#pragma unroll
        for (int m = 0; m < 4; ++m)
#pragma unroll
            for (int n = 0; n < 4; ++n)
                acc[m][n] = __builtin_amdgcn_mfma_f32_16x16x32_bf16(
                    af[m], bfr[n], acc[m][n], 0, 0, 0);
    };

    stage(0, 0);
    stage(32, 1);                      // 8 VMEM in flight
    asm volatile("s_waitcnt vmcnt(4)" ::: "memory");   // tile 0 landed
    __builtin_amdgcn_sched_barrier(0);
    __builtin_amdgcn_s_barrier();
    __builtin_amdgcn_sched_barrier(0);

    int it = 0;
    for (int k0 = 0; k0 < Dk - 64; k0 += 32, ++it) {   // 30 iters
        stage(k0 + 64, (it + 2) % 3);  // in flight: k+1 (4), k+2 (4)
        compute(it % 3);
        asm volatile("s_waitcnt vmcnt(4)" ::: "memory");  // k+1 landed; k+2 floats
        __builtin_amdgcn_sched_barrier(0);
        __builtin_amdgcn_s_barrier();  // all waves done with buf it%3 + k+1 ready
        __builtin_amdgcn_sched_barrier(0);
    }
    // it == 30: compute k0 = Dk-64 (already waited), then last tile
    compute(it % 3);
    asm volatile("s_waitcnt vmcnt(0)" ::: "memory");
    __builtin_amdgcn_sched_barrier(0);
    __builtin_amdgcn_s_barrier();
    __builtin_amdgcn_sched_barrier(0);
    ++it;
    compute(it % 3);

#pragma unroll
    for (int m = 0; m < 4; ++m) {
#pragma unroll
        for (int n = 0; n < 4; ++n) {
            const int col = tn * 128 + wc + n * 16 + l15;
            float bv_ = 0.f;
            if (EPI == 6 || EPI == 7) bv_ = bias[col];
#pragma unroll
            for (int j = 0; j < 4; ++j) {
                const int rowl = wr + m * 16 + lq * 4 + j;
                const size_t idx = (size_t)(tm * 128 + rowl) * Dk + col;
                const float xv = acc[m][n][j];
                if constexpr (EPI == 0) {
                    ((__hip_bfloat16*)CoutV)[idx] =
                        __float2bfloat16(xv * sigmoidf_fast(xv));
                } else if constexpr (EPI == 1) {
                    ((float*)CoutV)[idx] = xv;
                } else if constexpr (EPI == 6) {
                    const float e = FAST_EXP2(-(xv + bv_) * LOG2E);
                    ((unsigned short*)CoutV)[idx * 2] = bf16_bits(e);
                } else {   // EPI == 7: tanh via exp2, sign-safe
                    const float y = xv + bv_;
                    const float e = FAST_EXP2(fabsf(y) * (2.f * LOG2E));
                    float t = 1.f - 2.f * FAST_RCP(e + 1.f);
                    t = copysignf(t, y);
                    ((unsigned short*)CoutV)[idx * 2 + 1] = bf16_bits(t);
                }
            }
        }
    }
}

// Sequential scan, cell fused (stores cell = h^2*sigmoid(h); cell ops are off
// the dependent chain). 128 blocks x 1 wave; LDS double-buffered EV chunks.
__global__ __launch_bounds__(64)
void scan_kernel(const unsigned int* __restrict__ EV,
                 const float* __restrict__ h0,
                 const float* __restrict__ dal,
                 __hip_bfloat16* __restrict__ cell, float* __restrict__ hfin)
{
    constexpr int CH  = 32;
    constexpr int NCH = TT / CH;   // 64
    __shared__ __align__(16) unsigned int lEV[2][CH * 64];

    const int tid = threadIdx.x;
    const int bx  = blockIdx.x;
    const int b   = bx >> 4;
    const int d0  = (bx & 15) * 64;
    const int d   = d0 + tid;
    const int g   = b * Dk + d;

    float h = h0[g];
    const float nl2 = -dal[d] * LOG2E;

    const size_t sbase = (size_t)b * TT * Dk + d0;

    const int sl = tid >> 4;
    const int co = (tid & 15) * 4;

    auto issue = [&](int ck, int buf) {
#pragma unroll
        for (int grp = 0; grp < 8; ++grp) {
            const size_t off = sbase + (size_t)(ck * CH + grp * 4 + sl) * Dk + co;
            gload_lds16(EV + off, (void*)&lEV[buf][grp * 256]);
        }
    };

    issue(0, 0);
    asm volatile("s_waitcnt vmcnt(0)" ::: "memory");
    __builtin_amdgcn_sched_barrier(0);

    for (int k = 0; k < NCH; ++k) {
        const int buf = k & 1;
        if (k + 1 < NCH) issue(k + 1, buf ^ 1);
        __builtin_amdgcn_sched_barrier(0);

        const size_t cbase = sbase + (size_t)(k * CH) * Dk + tid;
#pragma unroll
        for (int s = 0; s < CH; ++s) {
            const unsigned int wv = lEV[buf][s * 64 + tid];
            const float E = __uint_as_float(wv << 16);
            const float V = __uint_as_float(wv & 0xffff0000u);
            const float u  = FAST_EXP2(nl2 * h);
            const float al = FAST_RCP(fmaf(E, u, 1.f));
            h = fmaf(al, h - V, V);
            // cell = h^2 * sigmoid(h): off the dependent chain
            const float sg = FAST_RCP(1.f + FAST_EXP2(-h * LOG2E));
            cell[cbase + (size_t)s * Dk] = __float2bfloat16(h * h * sg);
        }
        __builtin_amdgcn_sched_barrier(0);
        if (k + 1 < NCH) {
            // FIFO: [8 loads of chunk k+1][32 stores]; vmcnt(32) retires loads
            asm volatile("s_waitcnt vmcnt(32)" ::: "memory");
        }
        __builtin_amdgcn_sched_barrier(0);
    }

    hfin[g] = h;
}

extern "C" void kernel_launch(void* const* d_in, const int* in_sizes, int n_in,
                              void* d_out, int out_size, void* d_ws, size_t ws_size,
                              hipStream_t stream)
{
    const float* x     = (const float*)d_in[0];
    const float* h0    = (const float*)d_in[1];
    const float* W_in  = (const float*)d_in[2];
    const float* W_al  = (const float*)d_in[3];
    const float* d_al  = (const float*)d_in[4];
    const float* b_al  = (const float*)d_in[5];
    const float* W_x   = (const float*)d_in[6];
    const float* b_v   = (const float*)d_in[7];
    const float* W_out = (const float*)d_in[8];

    float* out  = (float*)d_out;
    float* hfin = out + (size_t)MROWS * Dk;

    char* ws = (char*)d_ws;
    const size_t bfBuf = (size_t)MROWS * Dk * sizeof(__hip_bfloat16);  // 33.5 MB
    const size_t wBuf  = (size_t)Dk * Dk * sizeof(__hip_bfloat16);     // 2 MB

    __hip_bfloat16* xb    = (__hip_bfloat16*)(ws);
    __hip_bfloat16* Winb  = (__hip_bfloat16*)(ws + bfBuf);
    __hip_bfloat16* Walb  = (__hip_bfloat16*)(ws + bfBuf + wBuf);
    __hip_bfloat16* Wxb   = (__hip_bfloat16*)(ws + bfBuf + 2 * wBuf);
    __hip_bfloat16* Woutb = (__hip_bfloat16*)(ws + bfBuf + 3 * wBuf);
    char* rest = ws + bfBuf + 4 * wBuf;
    __hip_bfloat16* xproj = (__hip_bfloat16*)rest;                 // then cell
    unsigned int*   EVb   = (unsigned int*)(rest + bfBuf);         // 67 MB

    __hip_bfloat16* cellb = xproj;   // xproj dead after E/V GEMMs

    dim3 blk(256);
    cvt_f32_bf16<<<dim3(MROWS * Dk / 1024), blk, 0, stream>>>(x, xb, MROWS * Dk);
    cvt_w4<<<dim3(4096), blk, 0, stream>>>(W_in, W_al, W_x, W_out,
                                           Winb, Walb, Wxb, Woutb);

    dim3 grid(1024);
    gemm_bt<0><<<grid, blk, 0, stream>>>(xb,    Winb,  nullptr, xproj);
    gemm_bt<6><<<grid, blk, 0, stream>>>(xproj, Walb,  b_al,    EVb);
    gemm_bt<7><<<grid, blk, 0, stream>>>(xproj, Wxb,   b_v,     EVb);
    scan_kernel<<<dim3(128), dim3(64), 0, stream>>>(EVb, h0, d_al, cellb, hfin);
    gemm_bt<1><<<grid, blk, 0, stream>>>(cellb, Woutb, nullptr, out);
}

// Round 9
// 300.377 us; speedup vs baseline: 1.1474x; 1.1474x over previous
//
#include <hip/hip_runtime.h>
#include <hip/hip_bf16.h>

typedef __attribute__((ext_vector_type(8))) short short8;
typedef __attribute__((ext_vector_type(4))) short short4v;
typedef __attribute__((ext_vector_type(4))) float f32x4;

#define Dk 1024
#define TT 2048
#define BB 8
#define MROWS (BB * TT)   // 16384
#define LOG2E 1.44269504088896f

#if defined(__has_builtin)
#if __has_builtin(__builtin_amdgcn_rcpf)
#define FAST_RCP(x) __builtin_amdgcn_rcpf(x)
#endif
#if __has_builtin(__builtin_amdgcn_exp2f)
#define FAST_EXP2(x) __builtin_amdgcn_exp2f(x)
#endif
#endif
#ifndef FAST_RCP
#define FAST_RCP(x) (1.f / (x))
#endif
#ifndef FAST_EXP2
#define FAST_EXP2(x) exp2f(x)
#endif

__device__ __forceinline__ void gload_lds16(const void* g, void* l) {
    __builtin_amdgcn_global_load_lds(
        (const __attribute__((address_space(1))) void*)g,
        (__attribute__((address_space(3))) void*)l, 16, 0, 0);
}

__device__ __forceinline__ float sigmoidf_fast(float x) {
    return FAST_RCP(1.f + FAST_EXP2(-x * LOG2E));
}

__device__ __forceinline__ unsigned short bf16_bits(float x) {
    union { __hip_bfloat16 h; unsigned short u; } c;
    c.h = __float2bfloat16(x);
    return c.u;
}

// One launch converts x (16384 chunk-blocks) + 4 weights (1024 each).
__global__ __launch_bounds__(256)
void cvt_all(const float* __restrict__ x,
             const float* __restrict__ w0, const float* __restrict__ w1,
             const float* __restrict__ w2, const float* __restrict__ w3,
             __hip_bfloat16* __restrict__ xo,
             __hip_bfloat16* __restrict__ o0, __hip_bfloat16* __restrict__ o1,
             __hip_bfloat16* __restrict__ o2, __hip_bfloat16* __restrict__ o3)
{
    const int bid = blockIdx.x;
    const float* in;
    __hip_bfloat16* out;
    int base;
    if (bid < 16384) {
        in = x; out = xo; base = bid * 1024;
    } else {
        const int wbid  = bid - 16384;
        const int which = wbid >> 10;
        in  = which == 0 ? w0 : which == 1 ? w1 : which == 2 ? w2 : w3;
        out = which == 0 ? o0 : which == 1 ? o1 : which == 2 ? o2 : o3;
        base = (wbid & 1023) * 1024;
    }
    const int i = base + threadIdx.x * 4;
    const float4 v = *(const float4*)(in + i);
    __hip_bfloat16 tmp[4];
    tmp[0] = __float2bfloat16(v.x);
    tmp[1] = __float2bfloat16(v.y);
    tmp[2] = __float2bfloat16(v.z);
    tmp[3] = __float2bfloat16(v.w);
    *(short4v*)(out + i) = *(const short4v*)tmp;
}

// C = epi(A * B^T). A: [M x 1024] bf16 rm, Bw: [1024 x 1024] bf16 rm.
// 2ph double-buffered LDS, stage-ahead, one barrier per K-iter (proven r7).
// EPI: 0 silu->bf16 | 1 plain->f32
//      6 E=exp(-(x+bias)) -> u16 @2*idx | 7 V=tanh(x+bias) -> u16 @2*idx+1
template<int EPI>
__global__ __launch_bounds__(256)
void gemm_bt(const __hip_bfloat16* __restrict__ A,
             const __hip_bfloat16* __restrict__ Bw,
             const float* __restrict__ bias,
             void* __restrict__ CoutV)
{
    __shared__ __hip_bfloat16 sA[2][128 * 32];
    __shared__ __hip_bfloat16 sB[2][128 * 32];

    const int tid  = threadIdx.x;
    const int bid  = blockIdx.x;
    const int nbid = (bid & 7) * 128 + (bid >> 3);   // XCD swizzle (1024%8==0)
    const int tn   = nbid & 7;
    const int tm   = nbid >> 3;
    const int lane = tid & 63;
    const int w    = tid >> 6;
    const int wr   = (w >> 1) * 64;
    const int wc   = (w & 1) * 64;
    const int l15  = lane & 15;
    const int lq   = lane >> 4;

    f32x4 acc[4][4];
#pragma unroll
    for (int m = 0; m < 4; ++m)
#pragma unroll
        for (int n = 0; n < 4; ++n)
            acc[m][n] = (f32x4){0.f, 0.f, 0.f, 0.f};

    const size_t baseA = (size_t)(tm * 128) * Dk;
    const size_t baseB = (size_t)(tn * 128) * Dk;

    auto stage = [&](int k0, int buf) {
#pragma unroll
        for (int i = 0; i < 2; ++i) {
            const int li  = i * 256 + tid;
            const int row = li >> 2;
            const int cb  = li & 3;
            const size_t go = (size_t)row * Dk + k0 + cb * 8;
            gload_lds16(A  + baseA + go, (char*)sA[buf] + li * 16);
            gload_lds16(Bw + baseB + go, (char*)sB[buf] + li * 16);
        }
    };

    stage(0, 0);
    __syncthreads();

    int buf = 0;
    for (int k0 = 0; k0 < Dk; k0 += 32) {
        if (k0 + 32 < Dk) stage(k0 + 32, buf ^ 1);   // issue BEFORE compute

        short8 af[4], bfr[4];
#pragma unroll
        for (int m = 0; m < 4; ++m)
            af[m] = *(const short8*)(sA[buf] + (wr + m * 16 + l15) * 32 + lq * 8);
#pragma unroll
        for (int n = 0; n < 4; ++n)
            bfr[n] = *(const short8*)(sB[buf] + (wc + n * 16 + l15) * 32 + lq * 8);

#pragma unroll
        for (int m = 0; m < 4; ++m)
#pragma unroll
            for (int n = 0; n < 4; ++n)
                acc[m][n] = __builtin_amdgcn_mfma_f32_16x16x32_bf16(
                    af[m], bfr[n], acc[m][n], 0, 0, 0);

        __syncthreads();   // one drain+barrier per iter, AFTER compute
        buf ^= 1;
    }

#pragma unroll
    for (int m = 0; m < 4; ++m) {
#pragma unroll
        for (int n = 0; n < 4; ++n) {
            const int col = tn * 128 + wc + n * 16 + l15;
            float bv_ = 0.f;
            if (EPI == 6 || EPI == 7) bv_ = bias[col];
#pragma unroll
            for (int j = 0; j < 4; ++j) {
                const int rowl = wr + m * 16 + lq * 4 + j;
                const size_t idx = (size_t)(tm * 128 + rowl) * Dk + col;
                const float xv = acc[m][n][j];
                if constexpr (EPI == 0) {
                    ((__hip_bfloat16*)CoutV)[idx] =
                        __float2bfloat16(xv * sigmoidf_fast(xv));
                } else if constexpr (EPI == 1) {
                    ((float*)CoutV)[idx] = xv;
                } else if constexpr (EPI == 6) {
                    const float e = FAST_EXP2(-(xv + bv_) * LOG2E);
                    ((unsigned short*)CoutV)[idx * 2] = bf16_bits(e);
                } else {   // EPI == 7: tanh via exp2, sign-safe
                    const float y = xv + bv_;
                    const float e = FAST_EXP2(fabsf(y) * (2.f * LOG2E));
                    float t = 1.f - 2.f * FAST_RCP(e + 1.f);
                    t = copysignf(t, y);
                    ((unsigned short*)CoutV)[idx * 2 + 1] = bf16_bits(t);
                }
            }
        }
    }
}

// Sequential scan in scaled space: track ht = nl2*h so the per-step dependent
// chain is exp2 -> fma -> rcp -> fma (no leading mul). V-scaling and h-recovery
// are off-chain. 128 blocks x 1 wave; LDS double-buffered EV chunks (proven r6).
__global__ __launch_bounds__(64)
void scan_kernel(const unsigned int* __restrict__ EV,
                 const float* __restrict__ h0,
                 const float* __restrict__ dal,
                 __hip_bfloat16* __restrict__ hout, float* __restrict__ hfin)
{
    constexpr int CH  = 32;
    constexpr int NCH = TT / CH;   // 64
    __shared__ __align__(16) unsigned int lEV[2][CH * 64];

    const int tid = threadIdx.x;
    const int bx  = blockIdx.x;
    const int b   = bx >> 4;
    const int d0  = (bx & 15) * 64;
    const int d   = d0 + tid;
    const int g   = b * Dk + d;

    float nl2 = -dal[d] * LOG2E;
    if (fabsf(nl2) < 1e-18f) nl2 = -1e-18f;   // guard divide (d_alpha==0 edge)
    const float inv_nl2 = 1.f / nl2;
    float ht = h0[g] * nl2;                    // scaled state

    const size_t sbase = (size_t)b * TT * Dk + d0;

    const int sl = tid >> 4;
    const int co = (tid & 15) * 4;

    auto issue = [&](int ck, int buf) {
#pragma unroll
        for (int grp = 0; grp < 8; ++grp) {
            const size_t off = sbase + (size_t)(ck * CH + grp * 4 + sl) * Dk + co;
            gload_lds16(EV + off, (void*)&lEV[buf][grp * 256]);
        }
    };

    issue(0, 0);
    asm volatile("s_waitcnt vmcnt(0)" ::: "memory");
    __builtin_amdgcn_sched_barrier(0);

    for (int k = 0; k < NCH; ++k) {
        const int buf = k & 1;
        if (k + 1 < NCH) issue(k + 1, buf ^ 1);
        __builtin_amdgcn_sched_barrier(0);

        const size_t cbase = sbase + (size_t)(k * CH) * Dk + tid;
#pragma unroll
        for (int s = 0; s < CH; ++s) {
            const unsigned int wv = lEV[buf][s * 64 + tid];
            const float E  = __uint_as_float(wv << 16);
            const float Vt = __uint_as_float(wv & 0xffff0000u) * nl2;  // off-chain
            const float u  = FAST_EXP2(ht);                   // chain
            const float al = FAST_RCP(fmaf(E, u, 1.f));       // chain
            ht = fmaf(al, ht - Vt, Vt);                       // chain
            hout[cbase + (size_t)s * Dk] = __float2bfloat16(ht * inv_nl2); // off-chain
        }
        __builtin_amdgcn_sched_barrier(0);
        if (k + 1 < NCH) {
            // FIFO: [8 loads of chunk k+1][32 stores]; vmcnt(32) retires loads
            asm volatile("s_waitcnt vmcnt(32)" ::: "memory");
        }
        __builtin_amdgcn_sched_barrier(0);
    }

    hfin[g] = ht * inv_nl2;
}

// cell = h^2 * sigmoid(h), bf16 -> bf16, 8 elems/thread, grid-stride
__global__ __launch_bounds__(256)
void gpass(const __hip_bfloat16* __restrict__ hin,
           __hip_bfloat16* __restrict__ cell, int n)
{
    const int stride = gridDim.x * 256 * 8;
    for (int i = (blockIdx.x * 256 + threadIdx.x) * 8; i < n; i += stride) {
        const short8 v = *(const short8*)(hin + i);
        short8 r;
#pragma unroll
        for (int j = 0; j < 8; ++j) {
            const float x = __uint_as_float(((unsigned int)(unsigned short)v[j]) << 16);
            const float s = sigmoidf_fast(x);
            r[j] = (short)bf16_bits(x * x * s);
        }
        *(short8*)(cell + i) = r;
    }
}

extern "C" void kernel_launch(void* const* d_in, const int* in_sizes, int n_in,
                              void* d_out, int out_size, void* d_ws, size_t ws_size,
                              hipStream_t stream)
{
    const float* x     = (const float*)d_in[0];
    const float* h0    = (const float*)d_in[1];
    const float* W_in  = (const float*)d_in[2];
    const float* W_al  = (const float*)d_in[3];
    const float* d_al  = (const float*)d_in[4];
    const float* b_al  = (const float*)d_in[5];
    const float* W_x   = (const float*)d_in[6];
    const float* b_v   = (const float*)d_in[7];
    const float* W_out = (const float*)d_in[8];

    float* out  = (float*)d_out;
    float* hfin = out + (size_t)MROWS * Dk;

    char* ws = (char*)d_ws;
    const size_t bfBuf = (size_t)MROWS * Dk * sizeof(__hip_bfloat16);  // 33.5 MB
    const size_t wBuf  = (size_t)Dk * Dk * sizeof(__hip_bfloat16);     // 2 MB

    __hip_bfloat16* xb    = (__hip_bfloat16*)(ws);                 // x bf16, then h
    __hip_bfloat16* Winb  = (__hip_bfloat16*)(ws + bfBuf);
    __hip_bfloat16* Walb  = (__hip_bfloat16*)(ws + bfBuf + wBuf);
    __hip_bfloat16* Wxb   = (__hip_bfloat16*)(ws + bfBuf + 2 * wBuf);
    __hip_bfloat16* Woutb = (__hip_bfloat16*)(ws + bfBuf + 3 * wBuf);
    char* rest = ws + bfBuf + 4 * wBuf;
    __hip_bfloat16* xproj = (__hip_bfloat16*)rest;                 // then cell
    unsigned int*   EVb   = (unsigned int*)(rest + bfBuf);         // 67 MB

    __hip_bfloat16* hbuf  = xb;      // x dead after GEMM1
    __hip_bfloat16* cellb = xproj;   // xproj dead after E/V GEMMs

    dim3 blk(256);
    cvt_all<<<dim3(16384 + 4096), blk, 0, stream>>>(
        x, W_in, W_al, W_x, W_out, xb, Winb, Walb, Wxb, Woutb);

    dim3 grid(1024);
    gemm_bt<0><<<grid, blk, 0, stream>>>(xb,    Winb,  nullptr, xproj);
    gemm_bt<6><<<grid, blk, 0, stream>>>(xproj, Walb,  b_al,    EVb);
    gemm_bt<7><<<grid, blk, 0, stream>>>(xproj, Wxb,   b_v,     EVb);
    scan_kernel<<<dim3(128), dim3(64), 0, stream>>>(EVb, h0, d_al, hbuf, hfin);
    gpass<<<dim3(2048), blk, 0, stream>>>(hbuf, cellb, MROWS * Dk);
    gemm_bt<1><<<grid, blk, 0, stream>>>(cellb, Woutb, nullptr, out);
}

// Round 10
// 279.663 us; speedup vs baseline: 1.2324x; 1.0741x over previous
//
#include <hip/hip_runtime.h>
#include <hip/hip_bf16.h>

typedef __attribute__((ext_vector_type(8))) short short8;
typedef __attribute__((ext_vector_type(4))) short short4v;
typedef __attribute__((ext_vector_type(4))) float f32x4;

#define Dk 1024
#define TT 2048
#define BB 8
#define MROWS (BB * TT)   // 16384
#define LOG2E 1.44269504088896f

#if defined(__has_builtin)
#if __has_builtin(__builtin_amdgcn_rcpf)
#define FAST_RCP(x) __builtin_amdgcn_rcpf(x)
#endif
#if __has_builtin(__builtin_amdgcn_exp2f)
#define FAST_EXP2(x) __builtin_amdgcn_exp2f(x)
#endif
#endif
#ifndef FAST_RCP
#define FAST_RCP(x) (1.f / (x))
#endif
#ifndef FAST_EXP2
#define FAST_EXP2(x) exp2f(x)
#endif

__device__ __forceinline__ void gload_lds16(const void* g, void* l) {
    __builtin_amdgcn_global_load_lds(
        (const __attribute__((address_space(1))) void*)g,
        (__attribute__((address_space(3))) void*)l, 16, 0, 0);
}

__device__ __forceinline__ float sigmoidf_fast(float x) {
    return FAST_RCP(1.f + FAST_EXP2(-x * LOG2E));
}

__device__ __forceinline__ unsigned short bf16_bits(float x) {
    union { __hip_bfloat16 h; unsigned short u; } c;
    c.h = __float2bfloat16(x);
    return c.u;
}

// One launch converts x (16384 chunk-blocks) + 4 weights (1024 each).
__global__ __launch_bounds__(256)
void cvt_all(const float* __restrict__ x,
             const float* __restrict__ w0, const float* __restrict__ w1,
             const float* __restrict__ w2, const float* __restrict__ w3,
             __hip_bfloat16* __restrict__ xo,
             __hip_bfloat16* __restrict__ o0, __hip_bfloat16* __restrict__ o1,
             __hip_bfloat16* __restrict__ o2, __hip_bfloat16* __restrict__ o3)
{
    const int bid = blockIdx.x;
    const float* in;
    __hip_bfloat16* out;
    int base;
    if (bid < 16384) {
        in = x; out = xo; base = bid * 1024;
    } else {
        const int wbid  = bid - 16384;
        const int which = wbid >> 10;
        in  = which == 0 ? w0 : which == 1 ? w1 : which == 2 ? w2 : w3;
        out = which == 0 ? o0 : which == 1 ? o1 : which == 2 ? o2 : o3;
        base = (wbid & 1023) * 1024;
    }
    const int i = base + threadIdx.x * 4;
    const float4 v = *(const float4*)(in + i);
    __hip_bfloat16 tmp[4];
    tmp[0] = __float2bfloat16(v.x);
    tmp[1] = __float2bfloat16(v.y);
    tmp[2] = __float2bfloat16(v.z);
    tmp[3] = __float2bfloat16(v.w);
    *(short4v*)(out + i) = *(const short4v*)tmp;
}

// 256x256-tile 8-wave GEMM, C = epi(A * B^T).
// BK=32, 3 LDS buffers (96KB), depth-2 prefetch, 2 phases/K-tile, counted
// vmcnt(4) boundaries (per-wave retire of next tile's own loads + s_barrier
// => global visibility), setprio around MFMA clusters, XOR-swizzled LDS
// (cb ^= row&3 within 64B rows; pre-swizzled global source + swizzled reads).
// EPI: 0 silu->bf16 | 1 plain->f32
//      6 E=exp(-(x+bias)) -> u16 @2*idx | 7 V=tanh(x+bias) -> u16 @2*idx+1
template<int EPI>
__global__ __launch_bounds__(512, 2)
void gemm256(const __hip_bfloat16* __restrict__ A,
             const __hip_bfloat16* __restrict__ Bw,
             const float* __restrict__ bias,
             void* __restrict__ CoutV)
{
    __shared__ __align__(16) char lds[3 * 32768];   // per buf: A 16KB | B 16KB

    const int tid  = threadIdx.x;         // 0..511
    const int bid  = blockIdx.x;
    const int nbid = (bid & 7) * 32 + (bid >> 3);   // XCD swizzle (256%8==0)
    const int tn   = nbid & 3;            // 4 col tiles
    const int tm   = nbid >> 2;           // 64 row tiles
    const int lane = tid & 63;
    const int w    = tid >> 6;            // 0..7
    const int wm   = w >> 2;              // 0..1  (M split)
    const int wn   = w & 3;               // 0..3  (N split)
    const int l15  = lane & 15;
    const int lq   = lane >> 4;

    const size_t baseA = (size_t)(tm * 256) * Dk;
    const size_t baseB = (size_t)(tn * 256) * Dk;

    // within-buffer byte offsets for swizzled fragment reads
    int offA[8], offB[4];
#pragma unroll
    for (int m = 0; m < 8; ++m) {
        const int row = wm * 128 + m * 16 + l15;
        offA[m] = (row * 4 + (lq ^ (row & 3))) * 16;
    }
#pragma unroll
    for (int n = 0; n < 4; ++n) {
        const int row = wn * 64 + n * 16 + l15;
        offB[n] = 16384 + (row * 4 + (lq ^ (row & 3))) * 16;
    }

    // stage half of K-tile kt into dst: phase 0 = A-tile, phase 1 = B-tile.
    // LDS slot s holds global (row = s>>2, cb = (s&3) ^ (row&3)) -> read-side
    // XOR cancels (both-sides involution).
    auto stagePh = [&](int kt, char* dst, int phase) {
#pragma unroll
        for (int j = 0; j < 2; ++j) {
            const int slot = (phase * 2 + j) * 512 + tid;
            const int s    = slot & 1023;
            const int row  = s >> 2;
            const int cb   = (s & 3) ^ (row & 3);
            const __hip_bfloat16* src =
                ((slot >> 10) ? Bw + baseB : A + baseA)
                + (size_t)row * Dk + kt * 32 + cb * 8;
            gload_lds16(src, dst + slot * 16);
        }
    };

    f32x4 acc[8][4];
#pragma unroll
    for (int m = 0; m < 8; ++m)
#pragma unroll
        for (int n = 0; n < 4; ++n)
            acc[m][n] = (f32x4){0.f, 0.f, 0.f, 0.f};

    char* b0 = lds;
    char* b1 = lds + 32768;
    char* b2 = lds + 65536;

    // prologue: stage tiles 0,1; retire tile 0 (vmcnt: 8 outstanding -> 4)
    stagePh(0, b0, 0); stagePh(0, b0, 1);
    stagePh(1, b1, 0); stagePh(1, b1, 1);
    asm volatile("s_waitcnt vmcnt(4)" ::: "memory");
    __builtin_amdgcn_s_barrier();

    char* cbuf = b0;   // compute tile t
    char* nbuf = b1;   // tile t+1 (in flight or landed)
    char* sbuf = b2;   // stage target for tile t+2

    for (int t = 0; t < 32; ++t) {
        short8 af[4], af2[4], bfr[4];

        // ---- phase 0: B frags + A frags m0-3, stage A of tile t+2 ----
#pragma unroll
        for (int n = 0; n < 4; ++n)
            bfr[n] = *(const short8*)(cbuf + offB[n]);
#pragma unroll
        for (int m = 0; m < 4; ++m)
            af[m] = *(const short8*)(cbuf + offA[m]);
        if (t < 30) stagePh(t + 2, sbuf, 0);
        __builtin_amdgcn_s_barrier();
        __builtin_amdgcn_s_setprio(1);
#pragma unroll
        for (int m = 0; m < 4; ++m)
#pragma unroll
            for (int n = 0; n < 4; ++n)
                acc[m][n] = __builtin_amdgcn_mfma_f32_16x16x32_bf16(
                    af[m], bfr[n], acc[m][n], 0, 0, 0);
        __builtin_amdgcn_s_setprio(0);
        __builtin_amdgcn_s_barrier();

        // ---- phase 1: A frags m4-7, stage B of tile t+2 ----
#pragma unroll
        for (int m = 0; m < 4; ++m)
            af2[m] = *(const short8*)(cbuf + offA[4 + m]);
        if (t < 30) stagePh(t + 2, sbuf, 1);
        __builtin_amdgcn_s_barrier();
        __builtin_amdgcn_s_setprio(1);
#pragma unroll
        for (int m = 0; m < 4; ++m)
#pragma unroll
            for (int n = 0; n < 4; ++n)
                acc[4 + m][n] = __builtin_amdgcn_mfma_f32_16x16x32_bf16(
                    af2[m], bfr[n], acc[4 + m][n], 0, 0, 0);
        __builtin_amdgcn_s_setprio(0);

        // ---- K-tile boundary: retire tile t+1's own 4 loads, keep t+2's
        //      in flight; barrier makes tile t+1 globally complete ----
        if (t < 30) {
            asm volatile("s_waitcnt vmcnt(4)" ::: "memory");
        } else if (t == 30) {
            asm volatile("s_waitcnt vmcnt(0)" ::: "memory");
        }
        if (t < 31) __builtin_amdgcn_s_barrier();

        char* tmp = cbuf; cbuf = nbuf; nbuf = sbuf; sbuf = tmp;
    }

    // epilogue
#pragma unroll
    for (int m = 0; m < 8; ++m) {
#pragma unroll
        for (int n = 0; n < 4; ++n) {
            const int col = tn * 256 + wn * 64 + n * 16 + l15;
            float bv_ = 0.f;
            if (EPI == 6 || EPI == 7) bv_ = bias[col];
#pragma unroll
            for (int j = 0; j < 4; ++j) {
                const int rowg = tm * 256 + wm * 128 + m * 16 + lq * 4 + j;
                const size_t idx = (size_t)rowg * Dk + col;
                const float xv = acc[m][n][j];
                if constexpr (EPI == 0) {
                    ((__hip_bfloat16*)CoutV)[idx] =
                        __float2bfloat16(xv * sigmoidf_fast(xv));
                } else if constexpr (EPI == 1) {
                    ((float*)CoutV)[idx] = xv;
                } else if constexpr (EPI == 6) {
                    const float e = FAST_EXP2(-(xv + bv_) * LOG2E);
                    ((unsigned short*)CoutV)[idx * 2] = bf16_bits(e);
                } else {   // EPI == 7: tanh via exp2, sign-safe
                    const float y = xv + bv_;
                    const float e = FAST_EXP2(fabsf(y) * (2.f * LOG2E));
                    float tv = 1.f - 2.f * FAST_RCP(e + 1.f);
                    tv = copysignf(tv, y);
                    ((unsigned short*)CoutV)[idx * 2 + 1] = bf16_bits(tv);
                }
            }
        }
    }
}

// Sequential scan in scaled space (proven r9). 128 blocks x 1 wave.
__global__ __launch_bounds__(64)
void scan_kernel(const unsigned int* __restrict__ EV,
                 const float* __restrict__ h0,
                 const float* __restrict__ dal,
                 __hip_bfloat16* __restrict__ hout, float* __restrict__ hfin)
{
    constexpr int CH  = 32;
    constexpr int NCH = TT / CH;   // 64
    __shared__ __align__(16) unsigned int lEV[2][CH * 64];

    const int tid = threadIdx.x;
    const int bx  = blockIdx.x;
    const int b   = bx >> 4;
    const int d0  = (bx & 15) * 64;
    const int d   = d0 + tid;
    const int g   = b * Dk + d;

    float nl2 = -dal[d] * LOG2E;
    if (fabsf(nl2) < 1e-18f) nl2 = -1e-18f;
    const float inv_nl2 = 1.f / nl2;
    float ht = h0[g] * nl2;

    const size_t sbase = (size_t)b * TT * Dk + d0;

    const int sl = tid >> 4;
    const int co = (tid & 15) * 4;

    auto issue = [&](int ck, int buf) {
#pragma unroll
        for (int grp = 0; grp < 8; ++grp) {
            const size_t off = sbase + (size_t)(ck * CH + grp * 4 + sl) * Dk + co;
            gload_lds16(EV + off, (void*)&lEV[buf][grp * 256]);
        }
    };

    issue(0, 0);
    asm volatile("s_waitcnt vmcnt(0)" ::: "memory");
    __builtin_amdgcn_sched_barrier(0);

    for (int k = 0; k < NCH; ++k) {
        const int buf = k & 1;
        if (k + 1 < NCH) issue(k + 1, buf ^ 1);
        __builtin_amdgcn_sched_barrier(0);

        const size_t cbase = sbase + (size_t)(k * CH) * Dk + tid;
#pragma unroll
        for (int s = 0; s < CH; ++s) {
            const unsigned int wv = lEV[buf][s * 64 + tid];
            const float E  = __uint_as_float(wv << 16);
            const float Vt = __uint_as_float(wv & 0xffff0000u) * nl2;
            const float u  = FAST_EXP2(ht);
            const float al = FAST_RCP(fmaf(E, u, 1.f));
            ht = fmaf(al, ht - Vt, Vt);
            hout[cbase + (size_t)s * Dk] = __float2bfloat16(ht * inv_nl2);
        }
        __builtin_amdgcn_sched_barrier(0);
        if (k + 1 < NCH) {
            asm volatile("s_waitcnt vmcnt(32)" ::: "memory");
        }
        __builtin_amdgcn_sched_barrier(0);
    }

    hfin[g] = ht * inv_nl2;
}

// cell = h^2 * sigmoid(h), bf16 -> bf16, 8 elems/thread, grid-stride
__global__ __launch_bounds__(256)
void gpass(const __hip_bfloat16* __restrict__ hin,
           __hip_bfloat16* __restrict__ cell, int n)
{
    const int stride = gridDim.x * 256 * 8;
    for (int i = (blockIdx.x * 256 + threadIdx.x) * 8; i < n; i += stride) {
        const short8 v = *(const short8*)(hin + i);
        short8 r;
#pragma unroll
        for (int j = 0; j < 8; ++j) {
            const float x = __uint_as_float(((unsigned int)(unsigned short)v[j]) << 16);
            const float s = sigmoidf_fast(x);
            r[j] = (short)bf16_bits(x * x * s);
        }
        *(short8*)(cell + i) = r;
    }
}

extern "C" void kernel_launch(void* const* d_in, const int* in_sizes, int n_in,
                              void* d_out, int out_size, void* d_ws, size_t ws_size,
                              hipStream_t stream)
{
    const float* x     = (const float*)d_in[0];
    const float* h0    = (const float*)d_in[1];
    const float* W_in  = (const float*)d_in[2];
    const float* W_al  = (const float*)d_in[3];
    const float* d_al  = (const float*)d_in[4];
    const float* b_al  = (const float*)d_in[5];
    const float* W_x   = (const float*)d_in[6];
    const float* b_v   = (const float*)d_in[7];
    const float* W_out = (const float*)d_in[8];

    float* out  = (float*)d_out;
    float* hfin = out + (size_t)MROWS * Dk;

    char* ws = (char*)d_ws;
    const size_t bfBuf = (size_t)MROWS * Dk * sizeof(__hip_bfloat16);  // 33.5 MB
    const size_t wBuf  = (size_t)Dk * Dk * sizeof(__hip_bfloat16);     // 2 MB

    __hip_bfloat16* xb    = (__hip_bfloat16*)(ws);                 // x bf16, then h
    __hip_bfloat16* Winb  = (__hip_bfloat16*)(ws + bfBuf);
    __hip_bfloat16* Walb  = (__hip_bfloat16*)(ws + bfBuf + wBuf);
    __hip_bfloat16* Wxb   = (__hip_bfloat16*)(ws + bfBuf + 2 * wBuf);
    __hip_bfloat16* Woutb = (__hip_bfloat16*)(ws + bfBuf + 3 * wBuf);
    char* rest = ws + bfBuf + 4 * wBuf;
    __hip_bfloat16* xproj = (__hip_bfloat16*)rest;                 // then cell
    unsigned int*   EVb   = (unsigned int*)(rest + bfBuf);         // 67 MB

    __hip_bfloat16* hbuf  = xb;      // x dead after GEMM1
    __hip_bfloat16* cellb = xproj;   // xproj dead after E/V GEMMs

    dim3 blk(256);
    cvt_all<<<dim3(16384 + 4096), blk, 0, stream>>>(
        x, W_in, W_al, W_x, W_out, xb, Winb, Walb, Wxb, Woutb);

    dim3 ggrid(256), gblk(512);
    gemm256<0><<<ggrid, gblk, 0, stream>>>(xb,    Winb,  nullptr, xproj);
    gemm256<6><<<ggrid, gblk, 0, stream>>>(xproj, Walb,  b_al,    EVb);
    gemm256<7><<<ggrid, gblk, 0, stream>>>(xproj, Wxb,   b_v,     EVb);
    scan_kernel<<<dim3(128), dim3(64), 0, stream>>>(EVb, h0, d_al, hbuf, hfin);
    gpass<<<dim3(2048), blk, 0, stream>>>(hbuf, cellb, MROWS * Dk);
    gemm256<1><<<ggrid, gblk, 0, stream>>>(cellb, Woutb, nullptr, out);
}

// Round 11
// 276.739 us; speedup vs baseline: 1.2454x; 1.0106x over previous
//
#include <hip/hip_runtime.h>
#include <hip/hip_bf16.h>

typedef __attribute__((ext_vector_type(8))) short short8;
typedef __attribute__((ext_vector_type(4))) short short4v;
typedef __attribute__((ext_vector_type(4))) float f32x4;

#define Dk 1024
#define TT 2048
#define BB 8
#define MROWS (BB * TT)   // 16384
#define LOG2E 1.44269504088896f

#if defined(__has_builtin)
#if __has_builtin(__builtin_amdgcn_rcpf)
#define FAST_RCP(x) __builtin_amdgcn_rcpf(x)
#endif
#if __has_builtin(__builtin_amdgcn_exp2f)
#define FAST_EXP2(x) __builtin_amdgcn_exp2f(x)
#endif
#endif
#ifndef FAST_RCP
#define FAST_RCP(x) (1.f / (x))
#endif
#ifndef FAST_EXP2
#define FAST_EXP2(x) exp2f(x)
#endif

__device__ __forceinline__ void gload_lds16(const void* g, void* l) {
    __builtin_amdgcn_global_load_lds(
        (const __attribute__((address_space(1))) void*)g,
        (__attribute__((address_space(3))) void*)l, 16, 0, 0);
}

__device__ __forceinline__ float sigmoidf_fast(float x) {
    return FAST_RCP(1.f + FAST_EXP2(-x * LOG2E));
}

__device__ __forceinline__ unsigned short bf16_bits(float x) {
    union { __hip_bfloat16 h; unsigned short u; } c;
    c.h = __float2bfloat16(x);
    return c.u;
}

// One launch converts x (16384 chunk-blocks) + 4 weights (1024 each).
__global__ __launch_bounds__(256)
void cvt_all(const float* __restrict__ x,
             const float* __restrict__ w0, const float* __restrict__ w1,
             const float* __restrict__ w2, const float* __restrict__ w3,
             __hip_bfloat16* __restrict__ xo,
             __hip_bfloat16* __restrict__ o0, __hip_bfloat16* __restrict__ o1,
             __hip_bfloat16* __restrict__ o2, __hip_bfloat16* __restrict__ o3)
{
    const int bid = blockIdx.x;
    const float* in;
    __hip_bfloat16* out;
    int base;
    if (bid < 16384) {
        in = x; out = xo; base = bid * 1024;
    } else {
        const int wbid  = bid - 16384;
        const int which = wbid >> 10;
        in  = which == 0 ? w0 : which == 1 ? w1 : which == 2 ? w2 : w3;
        out = which == 0 ? o0 : which == 1 ? o1 : which == 2 ? o2 : o3;
        base = (wbid & 1023) * 1024;
    }
    const int i = base + threadIdx.x * 4;
    const float4 v = *(const float4*)(in + i);
    __hip_bfloat16 tmp[4];
    tmp[0] = __float2bfloat16(v.x);
    tmp[1] = __float2bfloat16(v.y);
    tmp[2] = __float2bfloat16(v.z);
    tmp[3] = __float2bfloat16(v.w);
    *(short4v*)(out + i) = *(const short4v*)tmp;
}

// 256x256-tile 8-wave GEMM, C = epi(A * B^T).  (proven r10 structure)
// BK=32, 3 LDS buffers, depth-2 prefetch, counted vmcnt(4), setprio,
// both-sides XOR swizzle.
// EPI: 0 silu->bf16 | 1 plain->f32
//      6 E=exp(-(x+bias)) -> u16 @2*idx | 7 V=tanh(x+bias) -> u16 @2*idx+1
template<int EPI>
__global__ __launch_bounds__(512, 2)
void gemm256(const __hip_bfloat16* __restrict__ A,
             const __hip_bfloat16* __restrict__ Bw,
             const float* __restrict__ bias,
             void* __restrict__ CoutV)
{
    __shared__ __align__(16) char lds[3 * 32768];   // per buf: A 16KB | B 16KB

    const int tid  = threadIdx.x;         // 0..511
    const int bid  = blockIdx.x;
    const int nbid = (bid & 7) * 32 + (bid >> 3);   // XCD swizzle (256%8==0)
    const int tn   = nbid & 3;            // 4 col tiles
    const int tm   = nbid >> 2;           // 64 row tiles
    const int lane = tid & 63;
    const int w    = tid >> 6;            // 0..7
    const int wm   = w >> 2;              // 0..1  (M split)
    const int wn   = w & 3;               // 0..3  (N split)
    const int l15  = lane & 15;
    const int lq   = lane >> 4;

    const size_t baseA = (size_t)(tm * 256) * Dk;
    const size_t baseB = (size_t)(tn * 256) * Dk;

    int offA[8], offB[4];
#pragma unroll
    for (int m = 0; m < 8; ++m) {
        const int row = wm * 128 + m * 16 + l15;
        offA[m] = (row * 4 + (lq ^ (row & 3))) * 16;
    }
#pragma unroll
    for (int n = 0; n < 4; ++n) {
        const int row = wn * 64 + n * 16 + l15;
        offB[n] = 16384 + (row * 4 + (lq ^ (row & 3))) * 16;
    }

    auto stagePh = [&](int kt, char* dst, int phase) {
#pragma unroll
        for (int j = 0; j < 2; ++j) {
            const int slot = (phase * 2 + j) * 512 + tid;
            const int s    = slot & 1023;
            const int row  = s >> 2;
            const int cb   = (s & 3) ^ (row & 3);
            const __hip_bfloat16* src =
                ((slot >> 10) ? Bw + baseB : A + baseA)
                + (size_t)row * Dk + kt * 32 + cb * 8;
            gload_lds16(src, dst + slot * 16);
        }
    };

    f32x4 acc[8][4];
#pragma unroll
    for (int m = 0; m < 8; ++m)
#pragma unroll
        for (int n = 0; n < 4; ++n)
            acc[m][n] = (f32x4){0.f, 0.f, 0.f, 0.f};

    char* b0 = lds;
    char* b1 = lds + 32768;
    char* b2 = lds + 65536;

    stagePh(0, b0, 0); stagePh(0, b0, 1);
    stagePh(1, b1, 0); stagePh(1, b1, 1);
    asm volatile("s_waitcnt vmcnt(4)" ::: "memory");
    __builtin_amdgcn_s_barrier();

    char* cbuf = b0;
    char* nbuf = b1;
    char* sbuf = b2;

    for (int t = 0; t < 32; ++t) {
        short8 af[4], af2[4], bfr[4];

#pragma unroll
        for (int n = 0; n < 4; ++n)
            bfr[n] = *(const short8*)(cbuf + offB[n]);
#pragma unroll
        for (int m = 0; m < 4; ++m)
            af[m] = *(const short8*)(cbuf + offA[m]);
        if (t < 30) stagePh(t + 2, sbuf, 0);
        __builtin_amdgcn_s_barrier();
        __builtin_amdgcn_s_setprio(1);
#pragma unroll
        for (int m = 0; m < 4; ++m)
#pragma unroll
            for (int n = 0; n < 4; ++n)
                acc[m][n] = __builtin_amdgcn_mfma_f32_16x16x32_bf16(
                    af[m], bfr[n], acc[m][n], 0, 0, 0);
        __builtin_amdgcn_s_setprio(0);
        __builtin_amdgcn_s_barrier();

#pragma unroll
        for (int m = 0; m < 4; ++m)
            af2[m] = *(const short8*)(cbuf + offA[4 + m]);
        if (t < 30) stagePh(t + 2, sbuf, 1);
        __builtin_amdgcn_s_barrier();
        __builtin_amdgcn_s_setprio(1);
#pragma unroll
        for (int m = 0; m < 4; ++m)
#pragma unroll
            for (int n = 0; n < 4; ++n)
                acc[4 + m][n] = __builtin_amdgcn_mfma_f32_16x16x32_bf16(
                    af2[m], bfr[n], acc[4 + m][n], 0, 0, 0);
        __builtin_amdgcn_s_setprio(0);

        if (t < 30) {
            asm volatile("s_waitcnt vmcnt(4)" ::: "memory");
        } else if (t == 30) {
            asm volatile("s_waitcnt vmcnt(0)" ::: "memory");
        }
        if (t < 31) __builtin_amdgcn_s_barrier();

        char* tmp = cbuf; cbuf = nbuf; nbuf = sbuf; sbuf = tmp;
    }

#pragma unroll
    for (int m = 0; m < 8; ++m) {
#pragma unroll
        for (int n = 0; n < 4; ++n) {
            const int col = tn * 256 + wn * 64 + n * 16 + l15;
            float bv_ = 0.f;
            if (EPI == 6 || EPI == 7) bv_ = bias[col];
#pragma unroll
            for (int j = 0; j < 4; ++j) {
                const int rowg = tm * 256 + wm * 128 + m * 16 + lq * 4 + j;
                const size_t idx = (size_t)rowg * Dk + col;
                const float xv = acc[m][n][j];
                if constexpr (EPI == 0) {
                    ((__hip_bfloat16*)CoutV)[idx] =
                        __float2bfloat16(xv * sigmoidf_fast(xv));
                } else if constexpr (EPI == 1) {
                    ((float*)CoutV)[idx] = xv;
                } else if constexpr (EPI == 6) {
                    const float e = FAST_EXP2(-(xv + bv_) * LOG2E);
                    ((unsigned short*)CoutV)[idx * 2] = bf16_bits(e);
                } else {
                    const float y = xv + bv_;
                    const float e = FAST_EXP2(fabsf(y) * (2.f * LOG2E));
                    float tv = 1.f - 2.f * FAST_RCP(e + 1.f);
                    tv = copysignf(tv, y);
                    ((unsigned short*)CoutV)[idx * 2 + 1] = bf16_bits(tv);
                }
            }
        }
    }
}

// Producer-consumer scan: 128 blocks x 2 waves.
// Wave 0 (producer): pure dependent chain, writes scaled-state ht to LDS.
// Wave 1 (consumer): reads ht, computes cell = h^2*sigmoid(h) + stores (gpass
// folded in). Double-buffered ht handoff; one s_barrier per 32-step chunk
// on both paths (64 each). Producer-only vmcnt for the EV prefetch.
__global__ __launch_bounds__(128)
void scan_kernel(const unsigned int* __restrict__ EV,
                 const float* __restrict__ h0,
                 const float* __restrict__ dal,
                 __hip_bfloat16* __restrict__ cell, float* __restrict__ hfin)
{
    constexpr int CH  = 32;
    constexpr int NCH = TT / CH;   // 64
    __shared__ __align__(16) unsigned int lEV[2][CH * 64];
    __shared__ __align__(16) float        lH [2][CH * 64];

    const int tid  = threadIdx.x;         // 0..127
    const int wave = tid >> 6;
    const int lane = tid & 63;
    const int bx   = blockIdx.x;          // 0..127
    const int b    = bx >> 4;
    const int d0   = (bx & 15) * 64;
    const int d    = d0 + lane;
    const int g    = b * Dk + d;

    float nl2 = -dal[d] * LOG2E;
    if (fabsf(nl2) < 1e-18f) nl2 = -1e-18f;
    const float inv_nl2 = 1.f / nl2;

    const size_t sbase = (size_t)b * TT * Dk + d0;

    if (wave == 0) {
        // ---------------- producer: the recurrence chain ----------------
        float ht = h0[g] * nl2;

        const int sl = lane >> 4;
        const int co = (lane & 15) * 4;
        auto issue = [&](int ck, int buf) {
#pragma unroll
            for (int grp = 0; grp < 8; ++grp) {
                const size_t off = sbase + (size_t)(ck * CH + grp * 4 + sl) * Dk + co;
                gload_lds16(EV + off, (void*)&lEV[buf][grp * 256]);
            }
        };

        issue(0, 0);
        asm volatile("s_waitcnt vmcnt(0)" ::: "memory");
        __builtin_amdgcn_sched_barrier(0);

        for (int k = 0; k < NCH; ++k) {
            const int buf = k & 1;
            if (k + 1 < NCH) issue(k + 1, buf ^ 1);
            __builtin_amdgcn_sched_barrier(0);

#pragma unroll
            for (int s = 0; s < CH; ++s) {
                const unsigned int wv = lEV[buf][s * 64 + lane];
                const float E  = __uint_as_float(wv << 16);
                const float Vt = __uint_as_float(wv & 0xffff0000u) * nl2;
                const float u  = FAST_EXP2(ht);
                const float al = FAST_RCP(fmaf(E, u, 1.f));
                ht = fmaf(al, ht - Vt, Vt);
                lH[buf][s * 64 + lane] = ht;
            }
            __builtin_amdgcn_sched_barrier(0);
            // next chunk's EV loads landed; ht writes visible
            asm volatile("s_waitcnt vmcnt(0) lgkmcnt(0)" ::: "memory");
            __builtin_amdgcn_sched_barrier(0);
            __builtin_amdgcn_s_barrier();
        }
        hfin[g] = ht * inv_nl2;
    } else {
        // ---------------- consumer: epilogue + cell + stores ----------------
        for (int k = 0; k < NCH; ++k) {
            __builtin_amdgcn_s_barrier();
            __builtin_amdgcn_sched_barrier(0);
            const int buf = k & 1;
            const size_t cbase = sbase + (size_t)(k * CH) * Dk + lane;
#pragma unroll
            for (int s = 0; s < CH; ++s) {
                const float ht = lH[buf][s * 64 + lane];
                const float h  = ht * inv_nl2;
                const float sg = FAST_RCP(1.f + FAST_EXP2(-h * LOG2E));
                cell[cbase + (size_t)s * Dk] = __float2bfloat16(h * h * sg);
            }
        }
    }
}

extern "C" void kernel_launch(void* const* d_in, const int* in_sizes, int n_in,
                              void* d_out, int out_size, void* d_ws, size_t ws_size,
                              hipStream_t stream)
{
    const float* x     = (const float*)d_in[0];
    const float* h0    = (const float*)d_in[1];
    const float* W_in  = (const float*)d_in[2];
    const float* W_al  = (const float*)d_in[3];
    const float* d_al  = (const float*)d_in[4];
    const float* b_al  = (const float*)d_in[5];
    const float* W_x   = (const float*)d_in[6];
    const float* b_v   = (const float*)d_in[7];
    const float* W_out = (const float*)d_in[8];

    float* out  = (float*)d_out;
    float* hfin = out + (size_t)MROWS * Dk;

    char* ws = (char*)d_ws;
    const size_t bfBuf = (size_t)MROWS * Dk * sizeof(__hip_bfloat16);  // 33.5 MB
    const size_t wBuf  = (size_t)Dk * Dk * sizeof(__hip_bfloat16);     // 2 MB

    __hip_bfloat16* xb    = (__hip_bfloat16*)(ws);
    __hip_bfloat16* Winb  = (__hip_bfloat16*)(ws + bfBuf);
    __hip_bfloat16* Walb  = (__hip_bfloat16*)(ws + bfBuf + wBuf);
    __hip_bfloat16* Wxb   = (__hip_bfloat16*)(ws + bfBuf + 2 * wBuf);
    __hip_bfloat16* Woutb = (__hip_bfloat16*)(ws + bfBuf + 3 * wBuf);
    char* rest = ws + bfBuf + 4 * wBuf;
    __hip_bfloat16* xproj = (__hip_bfloat16*)rest;                 // then cell
    unsigned int*   EVb   = (unsigned int*)(rest + bfBuf);         // 67 MB

    __hip_bfloat16* cellb = xproj;   // xproj dead after E/V GEMMs

    dim3 blk(256);
    cvt_all<<<dim3(16384 + 4096), blk, 0, stream>>>(
        x, W_in, W_al, W_x, W_out, xb, Winb, Walb, Wxb, Woutb);

    dim3 ggrid(256), gblk(512);
    gemm256<0><<<ggrid, gblk, 0, stream>>>(xb,    Winb,  nullptr, xproj);
    gemm256<6><<<ggrid, gblk, 0, stream>>>(xproj, Walb,  b_al,    EVb);
    gemm256<7><<<ggrid, gblk, 0, stream>>>(xproj, Wxb,   b_v,     EVb);
    scan_kernel<<<dim3(128), dim3(128), 0, stream>>>(EVb, h0, d_al, cellb, hfin);
    gemm256<1><<<ggrid, gblk, 0, stream>>>(cellb, Woutb, nullptr, out);
}